// Round 7
// baseline (187.751 us; speedup 1.0000x reference)
//
#include <hip/hip_runtime.h>

#define N_NODES 100000
#define N_EDGES 1600000
#define D_FEAT 32
#define CAP 32                        // Poisson(16): P(deg>32) tiny -> spill path
#define NXCD 8
#define NODES_PER_XCD (N_NODES / NXCD)            // 12500
#define EDGE_THREADS (N_EDGES / 4)                // 400000 (4 edges/thread)
#define EDGE_BLOCKS ((EDGE_THREADS + 255) / 256)  // 1563

typedef int   __attribute__((ext_vector_type(4))) i32x4;
typedef float __attribute__((ext_vector_type(4))) f32x4;

// ---- pre-weight: weighted[n][f] = src_feats[n][f] * cj[n] (folds cj out of gather) ----
__global__ __launch_bounds__(256) void lgc_weight(
    const f32x4* __restrict__ feats4,   // [N_NODES * 8]
    const float* __restrict__ cj,       // [N_NODES]
    f32x4*       __restrict__ w4)       // [N_NODES * 8]
{
    int tid = blockIdx.x * 256 + threadIdx.x;   // exactly 800000
    float c = cj[tid >> 3];
    f32x4 v = __builtin_nontemporal_load(&feats4[tid]);
    w4[tid] = v * c;
}

// ---- bucket build: XCD x owns dst range; idx streams loaded NON-TEMPORALLY so
// they don't evict the L2-resident active bucket region (1.6 MB/XCD).
__global__ __launch_bounds__(256) void lgc_bucket(
    const i32x4* __restrict__ dst4,      // [N_EDGES/4]
    const i32x4* __restrict__ src4,      // [N_EDGES/4]
    const float* __restrict__ weighted,  // [N_NODES * 32] (for spill path)
    int*         __restrict__ cnt,       // [N_NODES], pre-zeroed
    int*         __restrict__ bucket,    // [N_NODES * CAP]
    float*       __restrict__ out)       // pre-zeroed; overflow spill target
{
    int x  = blockIdx.x % NXCD;          // dst-range this block handles
    int lb = blockIdx.x / NXCD;
    int t  = lb * 256 + threadIdx.x;
    if (t >= EDGE_THREADS) return;

    const int lo = x * NODES_PER_XCD;
    const int hi = lo + NODES_PER_XCD;

    i32x4 d4 = __builtin_nontemporal_load(&dst4[t]);
    bool ix = (d4.x >= lo) & (d4.x < hi);
    bool iy = (d4.y >= lo) & (d4.y < hi);
    bool iz = (d4.z >= lo) & (d4.z < hi);
    bool iw = (d4.w >= lo) & (d4.w < hi);
    if (!(ix | iy | iz | iw)) return;

    i32x4 s4 = __builtin_nontemporal_load(&src4[t]);
    int ds[4] = {d4.x, d4.y, d4.z, d4.w};
    int ss[4] = {s4.x, s4.y, s4.z, s4.w};
    bool in[4] = {ix, iy, iz, iw};

    #pragma unroll
    for (int k = 0; k < 4; ++k) {
        if (!in[k]) continue;
        int d = ds[k], s = ss[k];
        int pos = atomicAdd(&cnt[d], 1);
        if (pos < CAP) {
            bucket[(size_t)d * CAP + pos] = s;
        } else {
            // statistically-never overflow: spill weighted row into pre-zeroed out
            const float* row = weighted + (size_t)s * D_FEAT;
            float* o = out + (size_t)d * D_FEAT;
            for (int f = 0; f < D_FEAT; ++f) atomicAdd(o + f, row[f]);
        }
    }
}

// ---- gather-sum: lane = (node, float4-slice). One random 128B row per edge
// (cj pre-folded). Bucket rows + out are read/written non-temporally so L2
// stays dedicated to the weighted-feats table.
__global__ __launch_bounds__(256) void lgc_gather(
    const f32x4* __restrict__ w4,        // [N_NODES * 8] weighted feats
    const float* __restrict__ ci,
    const int*   __restrict__ cnt,
    const i32x4* __restrict__ bucket4,   // [N_NODES * CAP/4]
    f32x4*       __restrict__ out4)      // [N_NODES * 8]
{
    int tid = blockIdx.x * 256 + threadIdx.x;  // exactly 800000
    int n = tid >> 3;
    int f = tid & 7;

    int c = cnt[n];
    if (c > CAP) c = CAP;
    const i32x4* b4 = bucket4 + (size_t)n * (CAP / 4);

    // Prefetch the whole bucket row: 8 independent NT int4 loads.
    i32x4 r[8];
    #pragma unroll
    for (int j = 0; j < 8; ++j)
        if (j * 4 < c) r[j] = __builtin_nontemporal_load(&b4[j]);

    f32x4 acc = (f32x4)(0.f);
    #pragma unroll
    for (int j = 0; j < 8; ++j) {
        int base = j * 4;
        if (base < c) {
            i32x4 bv = r[j];
            acc += w4[(size_t)bv.x * 8 + f];
            if (base + 1 < c) acc += w4[(size_t)bv.y * 8 + f];
            if (base + 2 < c) acc += w4[(size_t)bv.z * 8 + f];
            if (base + 3 < c) acc += w4[(size_t)bv.w * 8 + f];
        }
    }

    float s = ci[n];
    f32x4 o = __builtin_nontemporal_load(&out4[tid]);   // overflow spill (normally 0)
    __builtin_nontemporal_store((acc + o) * s, &out4[tid]);
}

// ---------------- round-1 fallback path (only if ws too small) ----------------
__global__ __launch_bounds__(256) void lgc_scatter(
    const float4* __restrict__ src_feats4,
    const float*  __restrict__ cj,
    const int*    __restrict__ src_idx,
    const int*    __restrict__ dst_idx,
    float*        __restrict__ out)
{
    long tid = (long)blockIdx.x * blockDim.x + threadIdx.x;
    const long total = (long)N_EDGES * 8;
    if (tid >= total) return;
    int e  = (int)(tid >> 3);
    int f4 = (int)(tid & 7);
    int s = src_idx[e];
    int d = dst_idx[e];
    float c = cj[s];
    float4 v = src_feats4[s * 8 + f4];
    float* o = out + (size_t)d * D_FEAT + f4 * 4;
    atomicAdd(o + 0, v.x * c);
    atomicAdd(o + 1, v.y * c);
    atomicAdd(o + 2, v.z * c);
    atomicAdd(o + 3, v.w * c);
}

__global__ __launch_bounds__(256) void lgc_scale(
    float4*       __restrict__ out4,
    const float*  __restrict__ ci)
{
    int tid = blockIdx.x * blockDim.x + threadIdx.x;
    const int total = N_NODES * 8;
    if (tid >= total) return;
    float c = ci[tid >> 3];
    float4 v = out4[tid];
    v.x *= c; v.y *= c; v.z *= c; v.w *= c;
    out4[tid] = v;
}

extern "C" void kernel_launch(void* const* d_in, const int* in_sizes, int n_in,
                              void* d_out, int out_size, void* d_ws, size_t ws_size,
                              hipStream_t stream) {
    const float* src_feats = (const float*)d_in[0];   // [100000, 32] f32
    const float* cj        = (const float*)d_in[1];   // [100000, 1]
    const float* ci        = (const float*)d_in[2];   // [100000, 1]
    const int*   src_idx   = (const int*)d_in[3];     // [1600000]
    const int*   dst_idx   = (const int*)d_in[4];     // [1600000]
    float*       out       = (float*)d_out;           // [100000, 32] f32

    // ws layout: cnt[102400 ints] | bucket[N_NODES*CAP ints] | weighted[N_NODES*32 f32]
    const size_t cnt_ints    = 102400;                 // 0.4 MB
    const size_t bucket_ints = (size_t)N_NODES * CAP;  // 12.8 MB
    const size_t wfeat_flts  = (size_t)N_NODES * D_FEAT; // 12.8 MB
    const size_t need = (cnt_ints + bucket_ints + wfeat_flts) * 4;

    if (ws_size >= need) {
        int*   cnt      = (int*)d_ws;
        int*   bucket   = cnt + cnt_ints;
        float* weighted = (float*)(bucket + bucket_ints);

        hipMemsetAsync(cnt, 0, N_NODES * sizeof(int), stream);
        hipMemsetAsync(out, 0, (size_t)out_size * sizeof(float), stream);

        lgc_weight<<<(N_NODES * 8) / 256, 256, 0, stream>>>(
            (const f32x4*)src_feats, cj, (f32x4*)weighted);

        lgc_bucket<<<NXCD * EDGE_BLOCKS, 256, 0, stream>>>(
            (const i32x4*)dst_idx, (const i32x4*)src_idx, weighted,
            cnt, bucket, out);

        lgc_gather<<<(N_NODES * 8) / 256, 256, 0, stream>>>(
            (const f32x4*)weighted, ci, cnt, (const i32x4*)bucket, (f32x4*)out);
    } else {
        hipMemsetAsync(out, 0, (size_t)out_size * sizeof(float), stream);
        {
            const long total = (long)N_EDGES * 8;
            const int grid = (int)((total + 255) / 256);
            lgc_scatter<<<grid, 256, 0, stream>>>((const float4*)src_feats, cj,
                                                  src_idx, dst_idx, out);
        }
        {
            const int grid = (N_NODES * 8 + 255) / 256;
            lgc_scale<<<grid, 256, 0, stream>>>((float4*)out, ci);
        }
    }
}

// Round 8
// 176.137 us; speedup vs baseline: 1.0659x; 1.0659x over previous
//
#include <hip/hip_runtime.h>
#include <hip/hip_fp16.h>

#define N_NODES 100000
#define N_EDGES 1600000
#define D_FEAT 32
#define CAP 32                        // Poisson(16): P(deg>32) tiny -> spill path
#define NXCD 8
#define NODES_PER_XCD (N_NODES / NXCD)            // 12500
#define EDGE_THREADS (N_EDGES / 4)                // 400000 (4 edges/thread)
#define EDGE_BLOCKS ((EDGE_THREADS + 255) / 256)  // 1563

typedef int   __attribute__((ext_vector_type(4))) i32x4;
typedef float __attribute__((ext_vector_type(4))) f32x4;

// ---- pre-weight: w[n][f] = fp16(src_feats[n][f] * cj[n]) — halves the
// randomly-gathered table to 6.4 MB so it mostly fits a 4 MB per-XCD L2.
__global__ __launch_bounds__(256) void lgc_weight(
    const f32x4* __restrict__ feats4,   // [N_NODES * 8]
    const float* __restrict__ cj,       // [N_NODES]
    __half2*     __restrict__ w2)       // [N_NODES * 16]
{
    int tid = blockIdx.x * 256 + threadIdx.x;   // exactly 800000
    float c = cj[tid >> 3];
    f32x4 v = __builtin_nontemporal_load(&feats4[tid]);
    __half2 h0 = __floats2half2_rn(v.x * c, v.y * c);
    __half2 h1 = __floats2half2_rn(v.z * c, v.w * c);
    w2[tid * 2 + 0] = h0;
    w2[tid * 2 + 1] = h1;
}

// ---- bucket build: XCD x owns dst range [x*12500,(x+1)*12500); NT idx loads ----
__global__ __launch_bounds__(256) void lgc_bucket(
    const i32x4*  __restrict__ dst4,      // [N_EDGES/4]
    const i32x4*  __restrict__ src4,      // [N_EDGES/4]
    const __half* __restrict__ weighted,  // [N_NODES * 32] (spill path only)
    int*          __restrict__ cnt,       // [N_NODES], pre-zeroed
    int*          __restrict__ bucket,    // [N_NODES * CAP]
    float*        __restrict__ out)       // pre-zeroed; overflow spill target
{
    int x  = blockIdx.x % NXCD;
    int lb = blockIdx.x / NXCD;
    int t  = lb * 256 + threadIdx.x;
    if (t >= EDGE_THREADS) return;

    const int lo = x * NODES_PER_XCD;
    const int hi = lo + NODES_PER_XCD;

    i32x4 d4 = __builtin_nontemporal_load(&dst4[t]);
    bool ix = (d4.x >= lo) & (d4.x < hi);
    bool iy = (d4.y >= lo) & (d4.y < hi);
    bool iz = (d4.z >= lo) & (d4.z < hi);
    bool iw = (d4.w >= lo) & (d4.w < hi);
    if (!(ix | iy | iz | iw)) return;

    i32x4 s4 = __builtin_nontemporal_load(&src4[t]);
    int ds[4] = {d4.x, d4.y, d4.z, d4.w};
    int ss[4] = {s4.x, s4.y, s4.z, s4.w};
    bool in[4] = {ix, iy, iz, iw};

    #pragma unroll
    for (int k = 0; k < 4; ++k) {
        if (!in[k]) continue;
        int d = ds[k], s = ss[k];
        int pos = atomicAdd(&cnt[d], 1);
        if (pos < CAP) {
            bucket[(size_t)d * CAP + pos] = s;
        } else {
            // statistically-never overflow: spill fp16 weighted row into out
            const __half* row = weighted + (size_t)s * D_FEAT;
            float* o = out + (size_t)d * D_FEAT;
            for (int f = 0; f < D_FEAT; ++f)
                atomicAdd(o + f, __half2float(row[f]));
        }
    }
}

// ---- gather-sum: 4 lanes per node, each lane owns 8 feats (16B fp16 load per
// edge). Bucket row (8 int4) prefetched NT up-front; out written NT.
__global__ __launch_bounds__(256) void lgc_gather(
    const __half* __restrict__ w,        // [N_NODES * 32] fp16 weighted feats
    const float*  __restrict__ ci,
    const int*    __restrict__ cnt,
    const i32x4*  __restrict__ bucket4,  // [N_NODES * CAP/4]
    f32x4*        __restrict__ out4)     // [N_NODES * 8]
{
    int tid = blockIdx.x * 256 + threadIdx.x;
    if (tid >= N_NODES * 4) return;
    int n = tid >> 2;
    int q = tid & 3;                     // feat block: feats q*8 .. q*8+7

    int c = cnt[n];
    if (c > CAP) c = CAP;
    const i32x4* b4 = bucket4 + (size_t)n * (CAP / 4);

    i32x4 r[8];
    #pragma unroll
    for (int j = 0; j < 8; ++j)
        if (j * 4 < c) r[j] = __builtin_nontemporal_load(&b4[j]);

    float acc[8] = {0.f, 0.f, 0.f, 0.f, 0.f, 0.f, 0.f, 0.f};

    auto acc_row = [&](int s) {
        uint4 u = *reinterpret_cast<const uint4*>(w + (size_t)s * D_FEAT + q * 8);
        float2 f0 = __half22float2(*reinterpret_cast<__half2*>(&u.x));
        float2 f1 = __half22float2(*reinterpret_cast<__half2*>(&u.y));
        float2 f2 = __half22float2(*reinterpret_cast<__half2*>(&u.z));
        float2 f3 = __half22float2(*reinterpret_cast<__half2*>(&u.w));
        acc[0] += f0.x; acc[1] += f0.y; acc[2] += f1.x; acc[3] += f1.y;
        acc[4] += f2.x; acc[5] += f2.y; acc[6] += f3.x; acc[7] += f3.y;
    };

    #pragma unroll
    for (int j = 0; j < 8; ++j) {
        int base = j * 4;
        if (base < c) {
            i32x4 bv = r[j];
            acc_row(bv.x);
            if (base + 1 < c) acc_row(bv.y);
            if (base + 2 < c) acc_row(bv.z);
            if (base + 3 < c) acc_row(bv.w);
        }
    }

    float s = ci[n];
    size_t ob = (size_t)n * 8 + q * 2;
    f32x4 o0 = __builtin_nontemporal_load(&out4[ob]);      // spill (normally 0)
    f32x4 o1 = __builtin_nontemporal_load(&out4[ob + 1]);
    f32x4 a0 = {acc[0], acc[1], acc[2], acc[3]};
    f32x4 a1 = {acc[4], acc[5], acc[6], acc[7]};
    __builtin_nontemporal_store((a0 + o0) * s, &out4[ob]);
    __builtin_nontemporal_store((a1 + o1) * s, &out4[ob + 1]);
}

// ---------------- round-1 fallback path (only if ws too small) ----------------
__global__ __launch_bounds__(256) void lgc_scatter(
    const float4* __restrict__ src_feats4,
    const float*  __restrict__ cj,
    const int*    __restrict__ src_idx,
    const int*    __restrict__ dst_idx,
    float*        __restrict__ out)
{
    long tid = (long)blockIdx.x * blockDim.x + threadIdx.x;
    const long total = (long)N_EDGES * 8;
    if (tid >= total) return;
    int e  = (int)(tid >> 3);
    int f4 = (int)(tid & 7);
    int s = src_idx[e];
    int d = dst_idx[e];
    float c = cj[s];
    float4 v = src_feats4[s * 8 + f4];
    float* o = out + (size_t)d * D_FEAT + f4 * 4;
    atomicAdd(o + 0, v.x * c);
    atomicAdd(o + 1, v.y * c);
    atomicAdd(o + 2, v.z * c);
    atomicAdd(o + 3, v.w * c);
}

__global__ __launch_bounds__(256) void lgc_scale(
    float4*       __restrict__ out4,
    const float*  __restrict__ ci)
{
    int tid = blockIdx.x * blockDim.x + threadIdx.x;
    const int total = N_NODES * 8;
    if (tid >= total) return;
    float c = ci[tid >> 3];
    float4 v = out4[tid];
    v.x *= c; v.y *= c; v.z *= c; v.w *= c;
    out4[tid] = v;
}

extern "C" void kernel_launch(void* const* d_in, const int* in_sizes, int n_in,
                              void* d_out, int out_size, void* d_ws, size_t ws_size,
                              hipStream_t stream) {
    const float* src_feats = (const float*)d_in[0];   // [100000, 32] f32
    const float* cj        = (const float*)d_in[1];   // [100000, 1]
    const float* ci        = (const float*)d_in[2];   // [100000, 1]
    const int*   src_idx   = (const int*)d_in[3];     // [1600000]
    const int*   dst_idx   = (const int*)d_in[4];     // [1600000]
    float*       out       = (float*)d_out;           // [100000, 32] f32

    // ws layout: cnt[102400 ints] | bucket[N_NODES*CAP ints] | weighted[N_NODES*32 fp16]
    const size_t cnt_ints    = 102400;                    // 0.4 MB
    const size_t bucket_ints = (size_t)N_NODES * CAP;     // 12.8 MB
    const size_t wfeat_bytes = (size_t)N_NODES * D_FEAT * sizeof(__half); // 6.4 MB
    const size_t need = (cnt_ints + bucket_ints) * 4 + wfeat_bytes;

    if (ws_size >= need) {
        int*    cnt      = (int*)d_ws;
        int*    bucket   = cnt + cnt_ints;
        __half* weighted = (__half*)(bucket + bucket_ints);

        hipMemsetAsync(cnt, 0, N_NODES * sizeof(int), stream);
        hipMemsetAsync(out, 0, (size_t)out_size * sizeof(float), stream);

        lgc_weight<<<(N_NODES * 8) / 256, 256, 0, stream>>>(
            (const f32x4*)src_feats, cj, (__half2*)weighted);

        lgc_bucket<<<NXCD * EDGE_BLOCKS, 256, 0, stream>>>(
            (const i32x4*)dst_idx, (const i32x4*)src_idx, weighted,
            cnt, bucket, out);

        lgc_gather<<<(N_NODES * 4 + 255) / 256, 256, 0, stream>>>(
            weighted, ci, cnt, (const i32x4*)bucket, (f32x4*)out);
    } else {
        hipMemsetAsync(out, 0, (size_t)out_size * sizeof(float), stream);
        {
            const long total = (long)N_EDGES * 8;
            const int grid = (int)((total + 255) / 256);
            lgc_scatter<<<grid, 256, 0, stream>>>((const float4*)src_feats, cj,
                                                  src_idx, dst_idx, out);
        }
        {
            const int grid = (N_NODES * 8 + 255) / 256;
            lgc_scale<<<grid, 256, 0, stream>>>((float4*)out, ci);
        }
    }
}